// Round 9
// baseline (113.409 us; speedup 1.0000x reference)
//
#include <hip/hip_runtime.h>

typedef unsigned short u16;
typedef unsigned int u32;
typedef __bf16 bf16x8 __attribute__((ext_vector_type(8)));
typedef float f32x4 __attribute__((ext_vector_type(4)));
typedef u16 u16x8 __attribute__((ext_vector_type(8)));
typedef u32 u32x4 __attribute__((ext_vector_type(4)));

#define NB 64
#define NN 512
#define NH 12
#define HD 32
#define DIM 384

static constexpr size_t QWS = (size_t)NB * NH * NN * HD;  // bf16 elems per tensor
#define LOG2E 1.4426950408889634f
#define QSCALE 0.25503486f   // (1/sqrt(32)) * log2(e)

__device__ __forceinline__ u16 f2bf(float f) {
  __bf16 b = (__bf16)f;
  union { __bf16 b; u16 u; } v; v.b = b;
  return v.u;
}
__device__ __forceinline__ float lo16f(u32 w) {
  union { u32 u; float f; } v; v.u = w << 16;
  return v.f;
}
__device__ __forceinline__ float hi16f(u32 w) {
  union { u32 u; float f; } v; v.u = w & 0xffff0000u;
  return v.f;
}
__device__ __forceinline__ void gload16(const void* g, void* l) {
  __builtin_amdgcn_global_load_lds((const __attribute__((address_space(1))) u32*)g,
                                   (__attribute__((address_space(3))) u32*)l, 16, 0, 0);
}

// ---------------------------------------------------------------------------
// Kernel 1 (prep): blocks [0,6144): bias -> fragment-stream beR.
//                  blocks [6144,6360): W f32 -> fragment-stream Wf bf16:
//                  Wf[colblk 72][kk 12][lane 64][8], j = cb*16+lr, k = kk*32+lg*8+e.
// ---------------------------------------------------------------------------
__global__ __launch_bounds__(256) void prep_k(const float* __restrict__ table,
                                              const int* __restrict__ rel,
                                              const float* __restrict__ Wq,
                                              const float* __restrict__ Wkv,
                                              u32* __restrict__ beR,
                                              u16* __restrict__ Wf) {
  int bid = blockIdx.x;
  if (bid < 6144) {
    int t = bid * 256 + threadIdx.x;   // 1,572,864 words
    int word = t & 3;
    int lane = (t >> 2) & 63;
    int mf   = (t >> 8) & 3;
    int wv   = (t >> 10) & 7;
    int kt   = (t >> 13) & 15;
    int h    = t >> 17;
    int lr = lane & 15, lg = lane >> 4;
    int q = wv * 64 + mf * 16 + lr;
    int k = kt * 32 + (word >> 1) * 16 + lg * 4 + (word & 1) * 2;
    int i0 = rel[q * NN + k];
    int i1 = rel[q * NN + k + 1];
    u16 b0 = f2bf(table[i0 * NH + h] * LOG2E);
    u16 b1 = f2bf(table[i1 * NH + h] * LOG2E);
    beR[t] = (u32)b0 | ((u32)b1 << 16);
  } else {
    int t2 = (bid - 6144) * 256 + threadIdx.x;   // 0..55295
    int lane = t2 & 63;
    int kk = (t2 >> 6) % 12;
    int cb = t2 / (12 * 64);
    int j = cb * 16 + (lane & 15);
    int k = kk * 32 + (lane >> 4) * 8;
    const float* wrow = (j < 384) ? (Wq + (size_t)j * DIM) : (Wkv + (size_t)(j - 384) * DIM);
    float4 a = *(const float4*)(wrow + k);
    float4 b = *(const float4*)(wrow + k + 4);
    u16x8 o = {f2bf(a.x), f2bf(a.y), f2bf(a.z), f2bf(a.w),
               f2bf(b.x), f2bf(b.y), f2bf(b.z), f2bf(b.w)};
    *(u16x8*)(Wf + (size_t)t2 * 8) = o;
  }
}

// ---------------------------------------------------------------------------
// Kernel 2: QKV projection, fragment-stream W + register A.
//   768 blocks x 512 thr, all equal work: type = vv>>8 (0:q from x1, 1:k-half,
//   2:v-half from x2), 128 rows x 24 colblks = 12 chunks each. 3 blocks/CU.
//   Wave w owns rows m0+w*16..+15 in registers; W double-buffered 24KB chunks
//   via global_load_lds; two interleaved MFMA chains (acc0/acc1) for ILP.
// ---------------------------------------------------------------------------
__global__ __launch_bounds__(512, 6) void qkv_proj_k(const float* __restrict__ x1,
                                                     const float* __restrict__ x2,
                                                     const float* __restrict__ qb,
                                                     const float* __restrict__ vb,
                                                     const u16* __restrict__ Wf,
                                                     u16* __restrict__ q_ws,
                                                     u16* __restrict__ k_ws,
                                                     u16* __restrict__ v_ws) {
  __shared__ __attribute__((aligned(16))) u16 Wbuf[2][12288];  // 2 x 24KB

  const int g = blockIdx.x;                  // 0..767
  const int vv = (g & 7) * 96 + (g >> 3);    // XCD-chunked, bijective (768 = 8*96)
  const int type = vv >> 8;                  // 0:q 1:k 2:v
  const int m0 = (vv & 255) * 128;
  const int tid = threadIdx.x, lane = tid & 63, w = tid >> 6;
  const int lg = lane >> 4, lr = lane & 15;
  const float* X = (type == 0) ? x1 : x2;
  const int cb0 = type * 24;
  const char* wsrc = (const char*)(Wf + (size_t)cb0 * 12 * 64 * 8);
  const int bb = m0 >> 9;

  // A fragments: rows m0 + w*16 + lr, all K, in registers (48 VGPR)
  bf16x8 af[12];
  const float* xrow = X + (size_t)(m0 + w * 16 + lr) * DIM + lg * 8;
#pragma unroll
  for (int kk = 0; kk < 12; ++kk) {
    float4 a = *(const float4*)(xrow + kk * 32);
    float4 b = *(const float4*)(xrow + kk * 32 + 4);
    af[kk] = (bf16x8){(__bf16)a.x, (__bf16)a.y, (__bf16)a.z, (__bf16)a.w,
                      (__bf16)b.x, (__bf16)b.y, (__bf16)b.z, (__bf16)b.w};
  }

  // stage chunk 0
#pragma unroll
  for (int i = 0; i < 3; ++i) {
    int inst = w + i * 8;
    gload16(wsrc + inst * 1024 + lane * 16, (char*)&Wbuf[0][0] + inst * 1024 + lane * 16);
  }
  __syncthreads();

  // epilogue constants (single destination per block type)
  u16* dst = (type == 0) ? q_ws : (type == 1 ? k_ws : v_ws);
  const float scale = (type == 0) ? QSCALE : 1.0f;
  const int rowb = (m0 & 511) + w * 16 + lg * 4;

  for (int c = 0; c < 12; ++c) {
    if (c + 1 < 12) {
      const char* s = wsrc + (size_t)(c + 1) * 24576;
      char* d = (char*)&Wbuf[(c + 1) & 1][0];
#pragma unroll
      for (int i = 0; i < 3; ++i) {
        int inst = w + i * 8;
        gload16(s + inst * 1024 + lane * 16, d + inst * 1024 + lane * 16);
      }
    }
    const u16* wb = &Wbuf[c & 1][0];
    f32x4 acc0 = {0.f, 0.f, 0.f, 0.f};
    f32x4 acc1 = {0.f, 0.f, 0.f, 0.f};
#pragma unroll
    for (int kk = 0; kk < 12; ++kk) {
      bf16x8 wf0 = *(const bf16x8*)(wb + (kk * 64 + lane) * 8);
      bf16x8 wf1 = *(const bf16x8*)(wb + ((12 + kk) * 64 + lane) * 8);
      acc0 = __builtin_amdgcn_mfma_f32_16x16x32_bf16(af[kk], wf0, acc0, 0, 0, 0);
      acc1 = __builtin_amdgcn_mfma_f32_16x16x32_bf16(af[kk], wf1, acc1, 0, 0, 0);
    }
    // epilogue: colblks cb0 + 2c (acc0) and cb0 + 2c + 1 (acc1)
#pragma unroll
    for (int lc = 0; lc < 2; ++lc) {
      f32x4 acc = lc ? acc1 : acc0;
      int j = (cb0 + c * 2 + lc) * 16 + lr;
      int jj = (type == 0) ? j : (type == 1 ? j - 384 : j - 768);
      float bv = (type == 0) ? qb[jj] : (type == 2 ? vb[jj] : 0.0f);
      int hh = jj >> 5, dd = jj & 31;
      size_t basead = ((size_t)(bb * NH + hh) * NN) * HD + dd;
#pragma unroll
      for (int r = 0; r < 4; ++r)
        dst[basead + (size_t)(rowb + r) * HD] = f2bf((acc[r] + bv) * scale);
    }
    __syncthreads();
  }
}

// ---------------------------------------------------------------------------
// Kernel 3: attention (unchanged): swapped QK + k-permuted V,
// fragment-stream bias as MFMA C operand.
// ---------------------------------------------------------------------------
__global__ __launch_bounds__(512, 4) void attn_k(const u16* __restrict__ qw,
                                                 const u16* __restrict__ kw,
                                                 const u16* __restrict__ vw,
                                                 const u32* __restrict__ beR,
                                                 float* __restrict__ out) {
  const int g = blockIdx.x;                 // 0..767
  const int vv = (g & 7) * 96 + (g >> 3);   // chunk per XCD
  const int h = vv >> 6, b = vv & 63;
  const size_t base = ((size_t)b * NH + h) * NN * HD;
  const u16* Q = qw + base;
  const u16* K = kw + base;
  const u16* V = vw + base;

  __shared__ u16 Ks[NN][40];     // [k][d], 80B stride
  __shared__ u16 Vtp[HD][520];   // [d][k-permuted], 1040B stride

  const int tid = threadIdx.x;
  const int lane = tid & 63, w = tid >> 6;
  const int lg = lane >> 4, lr = lane & 15;
  const int q0 = w * 64;

  bf16x8 qf[4];
#pragma unroll
  for (int mf = 0; mf < 4; ++mf)
    qf[mf] = *(const bf16x8*)&Q[(q0 + mf * 16 + lr) * HD + lg * 8];

  for (int c = tid; c < 2048; c += 512) {
    int row = c >> 2, part = (c & 3) * 8;
    *(u16x8*)&Ks[row][part] = *(const u16x8*)&K[row * HD + part];
    u16x8 vld = *(const u16x8*)&V[row * HD + part];
    int kk = row & 31;
    int col = (row & ~31) + ((kk >> 2) & 3) * 8 + (kk >> 4) * 4 + (kk & 3);
#pragma unroll
    for (int j = 0; j < 8; ++j) Vtp[part + j][col] = vld[j];
  }
  __syncthreads();

  const u32* bstream = beR + ((((size_t)h * 16) * 8 + w) * 4) * 256 + lane * 4;

  f32x4 accOT[4][2] = {};
  float lsum[4] = {0.f, 0.f, 0.f, 0.f};

  for (int kt = 0; kt < 16; ++kt) {
    const int k0 = kt * 32;
    const u32* bkt = bstream + (size_t)kt * 8192;
    bf16x8 kf0 = *(const bf16x8*)&Ks[k0 + lr][lg * 8];
    bf16x8 kf1 = *(const bf16x8*)&Ks[k0 + 16 + lr][lg * 8];
    bf16x8 vp0 = *(const bf16x8*)&Vtp[lr][k0 + lg * 8];
    bf16x8 vp1 = *(const bf16x8*)&Vtp[16 + lr][k0 + lg * 8];
#pragma unroll
    for (int mf = 0; mf < 4; ++mf) {
      u32x4 bbv = *(const u32x4*)(bkt + mf * 256);
      f32x4 c0 = {lo16f(bbv.x), hi16f(bbv.x), lo16f(bbv.y), hi16f(bbv.y)};
      f32x4 c1 = {lo16f(bbv.z), hi16f(bbv.z), lo16f(bbv.w), hi16f(bbv.w)};
      f32x4 s0 = __builtin_amdgcn_mfma_f32_16x16x32_bf16(kf0, qf[mf], c0, 0, 0, 0);
      f32x4 s1 = __builtin_amdgcn_mfma_f32_16x16x32_bf16(kf1, qf[mf], c1, 0, 0, 0);
      float p0[4], p1[4];
#pragma unroll
      for (int r = 0; r < 4; ++r) {
        p0[r] = __builtin_amdgcn_exp2f(s0[r]);
        p1[r] = __builtin_amdgcn_exp2f(s1[r]);
      }
      lsum[mf] += ((p0[0] + p0[1]) + (p0[2] + p0[3])) +
                  ((p1[0] + p1[1]) + (p1[2] + p1[3]));
      bf16x8 pv = {(__bf16)p0[0], (__bf16)p0[1], (__bf16)p0[2], (__bf16)p0[3],
                   (__bf16)p1[0], (__bf16)p1[1], (__bf16)p1[2], (__bf16)p1[3]};
      accOT[mf][0] = __builtin_amdgcn_mfma_f32_16x16x32_bf16(vp0, pv, accOT[mf][0], 0, 0, 0);
      accOT[mf][1] = __builtin_amdgcn_mfma_f32_16x16x32_bf16(vp1, pv, accOT[mf][1], 0, 0, 0);
    }
  }

  float linv[4];
#pragma unroll
  for (int mf = 0; mf < 4; ++mf) {
    float s = lsum[mf];
    s += __shfl_xor(s, 16, 64);
    s += __shfl_xor(s, 32, 64);
    linv[mf] = 1.0f / s;
  }

  float* outp = out + ((size_t)b * NN) * DIM + h * HD;
#pragma unroll
  for (int mf = 0; mf < 4; ++mf) {
    int q = q0 + mf * 16 + lr;
#pragma unroll
    for (int nf = 0; nf < 2; ++nf) {
      float4 o = {accOT[mf][nf][0] * linv[mf], accOT[mf][nf][1] * linv[mf],
                  accOT[mf][nf][2] * linv[mf], accOT[mf][nf][3] * linv[mf]};
      *(float4*)&outp[(size_t)q * DIM + nf * 16 + lg * 4] = o;
    }
  }
}

// ---------------------------------------------------------------------------
extern "C" void kernel_launch(void* const* d_in, const int* in_sizes, int n_in,
                              void* d_out, int out_size, void* d_ws, size_t ws_size,
                              hipStream_t stream) {
  const float* x1    = (const float*)d_in[0];
  const float* x2    = (const float*)d_in[1];
  const float* Wq    = (const float*)d_in[2];
  const float* Wkv   = (const float*)d_in[3];
  const float* qb    = (const float*)d_in[4];
  const float* vb    = (const float*)d_in[5];
  const float* table = (const float*)d_in[6];
  const int*   rel   = (const int*)d_in[7];
  float* out = (float*)d_out;

  u16* ws   = (u16*)d_ws;
  u16* q_ws = ws;
  u16* k_ws = ws + QWS;
  u16* v_ws = ws + 2 * QWS;
  u32* beR  = (u32*)(ws + 3 * QWS);          // 1,572,864 u32 = 6.3 MB
  u16* Wf   = ws + 3 * QWS + 2 * 1572864;    // 442,368 u16 = 0.88 MB

  prep_k<<<6360, 256, 0, stream>>>(table, rel, Wq, Wkv, beR, Wf);
  qkv_proj_k<<<768, 512, 0, stream>>>(x1, x2, qb, vb, Wf, q_ws, k_ws, v_ws);
  attn_k<<<NB * NH, 512, 0, stream>>>(q_ws, k_ws, v_ws, beR, out);
}